// Round 10
// baseline (5752.128 us; speedup 1.0000x reference)
//
#include <hip/hip_runtime.h>
#include <math.h>

namespace {

constexpr int Bn = 64, Ln = 256, Cn = 8, Dn = 512, Mn = 512;
constexpr int TWO_M = 2 * Mn;        // 1024
constexpr int PCOLS = 2048;          // 1536 iou (+both biases) | 512 fx (+b_fx)
constexpr size_t P_FLOATS = (size_t)Bn * Ln * PCOLS;   // 33,554,432
constexpr size_t P_BYTES  = P_FLOATS * 4;              // 128 MB

__device__ __forceinline__ float sigmoidf_(float v) { return 1.0f / (1.0f + __expf(-v)); }
__device__ __forceinline__ float dot4_(float4 a, float4 b) {
    return a.x * b.x + a.y * b.y + a.z * b.z + a.w * b.w;
}

// ============================================================================
// proj2: P[r][0:1536] = x_r @ W_ioux.T + b_ioux + b_iouh
//        P[r][1536:2048] = x_r @ W_fx.T + b_fx        (r = b*Ln + t)
// ============================================================================
constexpr int PJLD = 36;

__global__ __launch_bounds__(256)
void proj2_kernel(const float* __restrict__ x,
                  const float* __restrict__ W_ioux, const float* __restrict__ b_ioux,
                  const float* __restrict__ b_iouh,
                  const float* __restrict__ W_fx, const float* __restrict__ b_fx,
                  float* __restrict__ P)
{
    __shared__ float sA[64 * PJLD];
    __shared__ float sB[64 * PJLD];
    const int tid = threadIdx.x;
    const int rb = blockIdx.x >> 5;       // 0..255
    const int cb = blockIdx.x & 31;       // 0..31
    const int r0 = rb * 64, c0 = cb * 64;
    const bool is_iou = (c0 < 3 * Mn);
    const int ri = tid & 15, ci = tid >> 4;

    float acc[4][4];
    #pragma unroll
    for (int r = 0; r < 4; ++r)
        #pragma unroll
        for (int c = 0; c < 4; ++c) acc[r][c] = 0.f;

    for (int k0 = 0; k0 < Dn; k0 += 32) {
        #pragma unroll
        for (int i = 0; i < 2; ++i) {
            const int flat = i * 256 + tid;           // 0..511
            const int row = flat >> 3, kq = flat & 7;
            *(float4*)&sA[row * PJLD + kq * 4] =
                *(const float4*)&x[(size_t)(r0 + row) * Dn + k0 + kq * 4];
            const float* wsrc = is_iou ? &W_ioux[(size_t)(c0 + row) * Dn]
                                       : &W_fx[(size_t)(c0 - 3 * Mn + row) * Dn];
            *(float4*)&sB[row * PJLD + kq * 4] = *(const float4*)&wsrc[k0 + kq * 4];
        }
        __syncthreads();
        #pragma unroll
        for (int k4 = 0; k4 < 8; ++k4) {
            float4 av[4], bv[4];
            #pragma unroll
            for (int r = 0; r < 4; ++r) av[r] = *(const float4*)&sA[(ri + r * 16) * PJLD + k4 * 4];
            #pragma unroll
            for (int c = 0; c < 4; ++c) bv[c] = *(const float4*)&sB[(ci + c * 16) * PJLD + k4 * 4];
            #pragma unroll
            for (int r = 0; r < 4; ++r)
                #pragma unroll
                for (int c = 0; c < 4; ++c) acc[r][c] += dot4_(av[r], bv[c]);
        }
        __syncthreads();
    }
    #pragma unroll
    for (int c = 0; c < 4; ++c) {
        const int col = c0 + ci + c * 16;
        const float bias = is_iou ? (b_ioux[col] + b_iouh[col]) : b_fx[col - 3 * Mn];
        #pragma unroll
        for (int r = 0; r < 4; ++r)
            P[(size_t)(r0 + ri + r * 16) * PCOLS + col] = acc[r][c] + bias;
    }
}

// ============================================================================
// persist8: persist7 + (1) h_sum fused into G2 (pass1 deleted; wave w holds
// batch w's 8 rows, shfl_xor(32) combines the rq pair), (2) gather indices
// prefetched per-thread into REGISTERS so loads issue immediately after the
// group barrier (no step-head syncthreads / LDS round trip).
// 256 blocks = 8 groups (bid&7, XCD-co-located) x 32 m-blocks.
// ============================================================================
// LDS carve (floats)
constexpr int R_W2  = 0;                  // W_fh slice:  f4[i16][jj4][32lane]  = 8192
constexpr int R_W1  = R_W2 + 8192;        // W_iouh slice: f4[(i*2+cc)*192+..]  = 24576
constexpr int R_HS  = R_W1 + 24576;       // h_sum 8x512  = 4096
constexpr int R_FD  = R_HS + 4096;        // G2 out 64x16 = 1024
constexpr int R_IO  = R_FD + 1024;        // G1 out 8x48  = 384
constexpr int R_CS  = R_IO + 384;         // c_s 64x16    = 1024
constexpr int R_PV  = R_CS + 1024;        // prev 8x32    = 256
constexpr int R_XMC = R_PV + 256;         // 64
constexpr int R_XM  = R_XMC + 64;         // 8
constexpr int R_FLOATS = R_XM + 8;        // 39624
constexpr size_t R_LDS_BYTES = (size_t)R_FLOATS * 4;   // 158,496 B
static_assert(R_LDS_BYTES <= 163840, "persist8 LDS over budget");

__global__ __launch_bounds__(512, 1)
void persist8_kernel(const int* __restrict__ x_c, const float* __restrict__ x_m,
                     const float* __restrict__ x_m_c,
                     const float* __restrict__ W_iouh, const float* __restrict__ W_fh,
                     const float* __restrict__ b_fh, const float* __restrict__ P,
                     float* __restrict__ out, unsigned* __restrict__ ctr)
{
    extern __shared__ float lds[];
    float* w2   = lds + R_W2;
    float* w1   = lds + R_W1;
    float* s_hs = lds + R_HS;
    float* s_fd = lds + R_FD;
    float* s_io = lds + R_IO;
    float* s_cs = lds + R_CS;
    float* s_pv = lds + R_PV;
    float* s_xmc = lds + R_XMC;
    float* s_xm  = lds + R_XM;

    const int tid = threadIdx.x;
    const int g  = blockIdx.x & 7;        // group varies fastest -> XCD co-location
    const int mt = blockIdx.x >> 3;       // 0..31
    const int m0 = mt * 16;
    const int b0 = g * 8;
    unsigned* myctr = ctr + g * 32;       // 128B-separated counters

    // ---- one-time: W_fh slice -> LDS, contiguous f4[i*128 + jj*32 + jh*8+ks] ----
    #pragma unroll
    for (int chk = 0; chk < 4; ++chk) {
        const int q = chk * 512 + tid;            // f4 id 0..2047
        const int i = q >> 7, jj = (q >> 5) & 3, lane32 = q & 31;
        const int jh = lane32 >> 3, ks = lane32 & 7;
        *(float4*)&w2[q * 4] =
            *(const float4*)&W_fh[(size_t)(m0 + jh * 4 + jj) * Dn + ks * 4 + i * 32];
    }
    // ---- one-time: W_iouh slice -> LDS, lane-linear f4[(i*2+cc)*192 + cq*8+ks] ----
    #pragma unroll
    for (int chk = 0; chk < 12; ++chk) {
        const int q = chk * 512 + tid;            // f4 id 0..6143
        const int i = q / 384, r1 = q % 384;
        const int cc = r1 / 192, lane192 = r1 % 192;
        const int cq = lane192 >> 3, ks = lane192 & 7;
        const int col = cq * 2 + cc, s = col >> 4, j = col & 15;
        *(float4*)&w1[q * 4] =
            *(const float4*)&W_iouh[(size_t)(s * Mn + m0 + j) * Mn + ks * 4 + i * 32];
    }

    // thread mappings
    const int g2_ks = tid & 7, g2_jh = (tid >> 3) & 3, g2_rq = tid >> 5;   // 16 rq x 4 jh x 8 ks
    const int g1_bq = tid / 192, g1_r = tid % 192;
    const int g1_cq = g1_r >> 3, g1_ks = g1_r & 7;                         // 2 bq x 24 cq x 8 ks
    const int cs_row = tid >> 2;                                           // tid<256: c_s row
    const bool hs_writer = ((tid & 56) == 0);                              // jh==0 && rq even

    const float bfh_j = b_fh[m0 + (tid & 15)];
    if (tid < 256) s_pv[tid] = 0.f;

    // ---- preload step t=1 per-thread indices + scalars + P into registers ----
    int   pf_idx[4]; float pf_xmc[4];
    int   cs_idx = 0;
    float sc_xmc = 0.f, sc_xm = 0.f;
    float p0 = 0.f, p1 = 0.f, p2 = 0.f, p3 = 0.f;
    #pragma unroll
    for (int r = 0; r < 4; ++r) {
        const int row = g2_rq * 4 + r;
        const size_t base = ((size_t)(b0 + (row >> 3)) * Ln + 1) * Cn + (row & 7);
        pf_idx[r] = x_c[base];
        pf_xmc[r] = x_m_c[base];
    }
    if (tid < 256)
        cs_idx = x_c[((size_t)(b0 + (cs_row >> 3)) * Ln + 1) * Cn + (cs_row & 7)];
    if (tid < 64)
        sc_xmc = x_m_c[((size_t)(b0 + (tid >> 3)) * Ln + 1) * Cn + (tid & 7)];
    else if (tid < 72)
        sc_xm = x_m[(size_t)(b0 + tid - 64) * Ln + 1];
    if (tid < 128) {
        const size_t prow = ((size_t)(b0 + (tid >> 4)) * Ln + 1) * (size_t)PCOLS
                            + m0 + (tid & 15);
        p0 = P[prow];           p1 = P[prow + Mn];
        p2 = P[prow + 2 * Mn];  p3 = P[prow + 3 * Mn];
    }
    __syncthreads();

    for (int t = 1; t < Ln; ++t) {
        // ---- step head: NO syncthreads — issue gathers straight from registers ----
        // commit gate-phase scalars (read only after the next syncthreads)
        if (tid < 64)      s_xmc[tid] = sc_xmc;
        else if (tid < 72) s_xm[tid - 64] = sc_xm;

        // c_s gather (own 16 cols; invalid idx -> zeroed row 0)
        if (tid < 256) {
            const int ci = (cs_idx < t) ? cs_idx : 0;
            const int q = tid & 3;
            const float4 v = *(const float4*)&out[((size_t)((b0 + (cs_row >> 3)) * Ln + ci))
                                                   * TWO_M + m0 + q * 4];
            *(float4*)&s_cs[cs_row * 16 + q * 4] = v;
        }

        // ---- G2 + fused h_sum: c_h(64x512) @ W_fh.T(16) ----
        {
            const float* rp[4];
            float wt[4];
            #pragma unroll
            for (int r = 0; r < 4; ++r) {
                const int row = g2_rq * 4 + r;
                const int ci = (pf_idx[r] < t) ? pf_idx[r] : 0;
                rp[r] = &out[((size_t)((b0 + (row >> 3)) * Ln + ci)) * TWO_M + Mn];
                wt[r] = pf_xmc[r];
            }
            float acc[4][4];
            #pragma unroll
            for (int r = 0; r < 4; ++r)
                #pragma unroll
                for (int jj = 0; jj < 4; ++jj) acc[r][jj] = 0.f;
            #pragma unroll 4
            for (int i = 0; i < 16; ++i) {
                const int k = g2_ks * 4 + i * 32;
                float4 cv[4], wv[4];
                #pragma unroll
                for (int r = 0; r < 4; ++r) cv[r] = *(const float4*)&rp[r][k];
                #pragma unroll
                for (int jj = 0; jj < 4; ++jj)
                    wv[jj] = *(const float4*)&w2[(i * 128 + jj * 32 + g2_jh * 8 + g2_ks) * 4];
                #pragma unroll
                for (int r = 0; r < 4; ++r)
                    #pragma unroll
                    for (int jj = 0; jj < 4; ++jj) acc[r][jj] += dot4_(cv[r], wv[jj]);
                // fused h_sum: this wave holds batch (tid>>6)'s 8 rows (rq pair)
                float4 hs;
                hs.x = wt[0] * cv[0].x + wt[1] * cv[1].x + wt[2] * cv[2].x + wt[3] * cv[3].x;
                hs.y = wt[0] * cv[0].y + wt[1] * cv[1].y + wt[2] * cv[2].y + wt[3] * cv[3].y;
                hs.z = wt[0] * cv[0].z + wt[1] * cv[1].z + wt[2] * cv[2].z + wt[3] * cv[3].z;
                hs.w = wt[0] * cv[0].w + wt[1] * cv[1].w + wt[2] * cv[2].w + wt[3] * cv[3].w;
                hs.x += __shfl_xor(hs.x, 32); hs.y += __shfl_xor(hs.y, 32);
                hs.z += __shfl_xor(hs.z, 32); hs.w += __shfl_xor(hs.w, 32);
                if (hs_writer)
                    *(float4*)&s_hs[(tid >> 6) * 512 + k] = hs;
            }
            #pragma unroll
            for (int r = 0; r < 4; ++r)
                #pragma unroll
                for (int jj = 0; jj < 4; ++jj) {
                    float v = acc[r][jj];
                    v += __shfl_xor(v, 1); v += __shfl_xor(v, 2); v += __shfl_xor(v, 4);
                    acc[r][jj] = v;
                }
            if (g2_ks == 0) {
                #pragma unroll
                for (int r = 0; r < 4; ++r)
                    *(float4*)&s_fd[(g2_rq * 4 + r) * 16 + g2_jh * 4] =
                        make_float4(acc[r][0], acc[r][1], acc[r][2], acc[r][3]);
            }
        }
        __syncthreads();   // s_hs ready for G1; s_fd/s_cs/s_xmc ready for gates

        // ---- G1: h_sum(8x512) @ W_iouh.T(48); 4 b x 2 cols x ks8 ----
        if (tid < 384) {
            float acc[2][4];
            #pragma unroll
            for (int cc = 0; cc < 2; ++cc)
                #pragma unroll
                for (int bb = 0; bb < 4; ++bb) acc[cc][bb] = 0.f;
            #pragma unroll 4
            for (int i = 0; i < 16; ++i) {
                const int k = g1_ks * 4 + i * 32;
                float4 hv[4];
                #pragma unroll
                for (int bb = 0; bb < 4; ++bb)
                    hv[bb] = *(const float4*)&s_hs[(g1_bq * 4 + bb) * 512 + k];
                #pragma unroll
                for (int cc = 0; cc < 2; ++cc) {
                    const float4 wv = *(const float4*)&w1[((i * 2 + cc) * 192
                                                           + g1_cq * 8 + g1_ks) * 4];
                    #pragma unroll
                    for (int bb = 0; bb < 4; ++bb) acc[cc][bb] += dot4_(hv[bb], wv);
                }
            }
            #pragma unroll
            for (int cc = 0; cc < 2; ++cc)
                #pragma unroll
                for (int bb = 0; bb < 4; ++bb) {
                    float v = acc[cc][bb];
                    v += __shfl_xor(v, 1); v += __shfl_xor(v, 2); v += __shfl_xor(v, 4);
                    acc[cc][bb] = v;
                }
            if (g1_ks == 0) {
                #pragma unroll
                for (int cc = 0; cc < 2; ++cc)
                    #pragma unroll
                    for (int bb = 0; bb < 4; ++bb)
                        s_io[(g1_bq * 4 + bb) * 48 + g1_cq * 2 + cc] = acc[cc][bb];
            }
        }

        // ---- prefetch next-step per-thread indices + scalars + P ----
        int   pf_idx_n[4]; float pf_xmc_n[4];
        int   cs_idx_n = 0;
        float sc_xmc_n = 0.f, sc_xm_n = 0.f;
        float np0 = 0.f, np1 = 0.f, np2 = 0.f, np3 = 0.f;
        #pragma unroll
        for (int r = 0; r < 4; ++r) { pf_idx_n[r] = 0; pf_xmc_n[r] = 0.f; }
        if (t < Ln - 1) {
            const int tn = t + 1;
            #pragma unroll
            for (int r = 0; r < 4; ++r) {
                const int row = g2_rq * 4 + r;
                const size_t base = ((size_t)(b0 + (row >> 3)) * Ln + tn) * Cn + (row & 7);
                pf_idx_n[r] = x_c[base];
                pf_xmc_n[r] = x_m_c[base];
            }
            if (tid < 256)
                cs_idx_n = x_c[((size_t)(b0 + (cs_row >> 3)) * Ln + tn) * Cn + (cs_row & 7)];
            if (tid < 64)
                sc_xmc_n = x_m_c[((size_t)(b0 + (tid >> 3)) * Ln + tn) * Cn + (tid & 7)];
            else if (tid < 72)
                sc_xm_n = x_m[(size_t)(b0 + tid - 64) * Ln + tn];
            if (tid < 128) {
                const size_t prow = ((size_t)(b0 + (tid >> 4)) * Ln + tn) * (size_t)PCOLS
                                    + m0 + (tid & 15);
                np0 = P[prow];           np1 = P[prow + Mn];
                np2 = P[prow + 2 * Mn];  np3 = P[prow + 3 * Mn];
            }
        }
        __syncthreads();   // s_io ready for gates

        // ---- gates, c/h, blend vs s_pv, store ----
        if (tid < 128) {
            const int b = tid >> 4, j = tid & 15;
            const float iv = s_io[b * 48 + j]      + p0;
            const float ov = s_io[b * 48 + 16 + j] + p1;
            const float uv = s_io[b * 48 + 32 + j] + p2;
            const float i_ = sigmoidf_(iv);
            const float o_ = sigmoidf_(ov);
            const float u_ = tanhf(uv);
            float facc = 0.f;
            #pragma unroll
            for (int c = 0; c < 8; ++c) {
                const int row = b * 8 + c;
                const float f = sigmoidf_(s_fd[row * 16 + j] + bfh_j + p3);
                facc += f * s_cs[row * 16 + j] * s_xmc[row];
            }
            const float cv = i_ * u_ + facc;
            const float hv = o_ * tanhf(cv);
            const float mv = s_xm[b];
            const float nc = mv * cv + (1.f - mv) * s_pv[b * 32 + j];
            const float nh = mv * hv + (1.f - mv) * s_pv[b * 32 + 16 + j];
            const size_t ob = ((size_t)(b0 + b) * Ln + t) * TWO_M;
            out[ob + m0 + j]      = nc;
            out[ob + Mn + m0 + j] = nh;
            s_pv[b * 32 + j]      = nc;
            s_pv[b * 32 + 16 + j] = nh;
        }
        __syncthreads();

        // ---- group barrier (release writes / acquire before next gather) ----
        if (t < Ln - 1) {
            if (tid == 0) {
                __hip_atomic_fetch_add(myctr, 1u, __ATOMIC_RELEASE, __HIP_MEMORY_SCOPE_AGENT);
                const unsigned target = 32u * (unsigned)t;
                while (__hip_atomic_load(myctr, __ATOMIC_RELAXED, __HIP_MEMORY_SCOPE_AGENT) < target)
                    __builtin_amdgcn_s_sleep(2);
                (void)__hip_atomic_load(myctr, __ATOMIC_ACQUIRE, __HIP_MEMORY_SCOPE_AGENT);
            }
            __syncthreads();
        }
        // rotate prefetched registers
        #pragma unroll
        for (int r = 0; r < 4; ++r) { pf_idx[r] = pf_idx_n[r]; pf_xmc[r] = pf_xmc_n[r]; }
        cs_idx = cs_idx_n; sc_xmc = sc_xmc_n; sc_xm = sc_xm_n;
        p0 = np0; p1 = np1; p2 = np2; p3 = np3;
    }
}

// ============================================================================
// Legacy monolithic step kernel (fallback when ws is too small for P)
// ============================================================================
constexpr int LBT = 4, LMT = 32, LNMT = Mn / LMT, LPAD = 4, LDK = Dn + LPAD;
constexpr int L_U16 = 4096, L_CHS = LBT * LDK, L_CH = LBT * Cn * LDK,
              L_WFH = LMT * LDK, L_CS = LBT * Cn * LMT, L_IOUF = 4 * LBT * LMT;
constexpr int L_FLOATS = L_U16 + L_CHS + L_CH + L_WFH + L_CS + L_IOUF + 32 + 4 + 32;
constexpr size_t L_BYTES = (size_t)L_FLOATS * 4;

__global__ __launch_bounds__(256, 1)
void step_legacy(const float* __restrict__ x, const int* __restrict__ x_c,
                 const float* __restrict__ x_m, const float* __restrict__ x_m_c,
                 const float* __restrict__ W_ioux, const float* __restrict__ b_ioux,
                 const float* __restrict__ W_iouh, const float* __restrict__ b_iouh,
                 const float* __restrict__ W_fx, const float* __restrict__ b_fx,
                 const float* __restrict__ W_fh, const float* __restrict__ b_fh,
                 float* __restrict__ out, int t)
{
    extern __shared__ float lds[];
    float* u16    = lds;
    float* s_chs  = u16 + L_U16;
    float* s_ch   = s_chs + L_CHS;
    float* s_wfh  = s_ch + L_CH;
    float* s_cs   = s_wfh + L_WFH;
    float* s_iouf = s_cs + L_CS;
    float* s_xmc  = s_iouf + L_IOUF;
    float* s_xm   = s_xmc + 32;
    int*   s_xc   = (int*)(s_xm + 4);

    const int tid = threadIdx.x;
    const int mt = blockIdx.x & (LNMT - 1);
    const int bt = blockIdx.x >> 4;
    const int b0 = bt * LBT, m0 = mt * LMT;

    #pragma unroll
    for (int i = 0; i < 8; ++i) {
        int flat = i * 256 + tid, b = flat >> 9, k = flat & 511;
        u16[b * LDK + k] = x[((size_t)(b0 + b) * Ln + t) * Dn + k];
    }
    if (tid < 32) {
        int b = tid >> 3, c = tid & 7;
        s_xc[tid]  = x_c[((size_t)(b0 + b) * Ln + t) * Cn + c];
        s_xmc[tid] = x_m_c[((size_t)(b0 + b) * Ln + t) * Cn + c];
    }
    if (tid < 4) s_xm[tid] = x_m[(size_t)(b0 + tid) * Ln + t];
    for (int i = 0; i < 64; ++i) {
        int flat = i * 256 + tid, j = flat >> 9, k = flat & 511;
        s_wfh[j * LDK + k] = W_fh[(size_t)(m0 + j) * Dn + k];
    }
    __syncthreads();

    #pragma unroll
    for (int i = 0; i < 8; ++i) {
        int flat = i * 256 + tid, b = flat >> 9, k = flat & 511;
        float acc = 0.f;
        #pragma unroll
        for (int c = 0; c < 8; ++c) {
            int idx = s_xc[b * 8 + c];
            float v = 0.f;
            if (idx < t) v = out[((size_t)(b0 + b) * Ln + idx) * TWO_M + Mn + k];
            s_ch[(b * 8 + c) * LDK + k] = v;
            acc += s_xmc[b * 8 + c] * v;
        }
        s_chs[b * LDK + k] = acc;
    }
    #pragma unroll
    for (int i = 0; i < 4; ++i) {
        int flat = i * 256 + tid;
        int b = flat >> 8, rem = flat & 255, c = rem >> 5, j = rem & 31;
        int idx = s_xc[b * 8 + c];
        float v = 0.f;
        if (idx < t) v = out[((size_t)(b0 + b) * Ln + idx) * TWO_M + m0 + j];
        s_cs[flat] = v;
    }
    __syncthreads();

    {
        const int unit = tid >> 3, ksl = tid & 7, s = unit >> 3, jg = unit & 7;
        float acc[4][4];
        #pragma unroll
        for (int b = 0; b < 4; ++b)
            #pragma unroll
            for (int jj = 0; jj < 4; ++jj) acc[b][jj] = 0.f;
        if (s < 3) {
            const int colbase = s * Mn + m0 + jg * 4;
            #pragma unroll 4
            for (int it = 0; it < 16; ++it) {
                const int k = it * 32 + ksl * 4;
                float4 sx[4], sc[4];
                #pragma unroll
                for (int b = 0; b < 4; ++b) {
                    sx[b] = *(const float4*)&u16[b * LDK + k];
                    sc[b] = *(const float4*)&s_chs[b * LDK + k];
                }
                #pragma unroll
                for (int jj = 0; jj < 4; ++jj) {
                    const float4 wx = *(const float4*)&W_ioux[(size_t)(colbase + jj) * Dn + k];
                    const float4 wh = *(const float4*)&W_iouh[(size_t)(colbase + jj) * Dn + k];
                    #pragma unroll
                    for (int b = 0; b < 4; ++b)
                        acc[b][jj] += dot4_(sx[b], wx) + dot4_(sc[b], wh);
                }
            }
        } else {
            const int colbase = m0 + jg * 4;
            #pragma unroll 4
            for (int it = 0; it < 16; ++it) {
                const int k = it * 32 + ksl * 4;
                float4 sx[4];
                #pragma unroll
                for (int b = 0; b < 4; ++b) sx[b] = *(const float4*)&u16[b * LDK + k];
                #pragma unroll
                for (int jj = 0; jj < 4; ++jj) {
                    const float4 wx = *(const float4*)&W_fx[(size_t)(colbase + jj) * Dn + k];
                    #pragma unroll
                    for (int b = 0; b < 4; ++b) acc[b][jj] += dot4_(sx[b], wx);
                }
            }
        }
        __syncthreads();
        #pragma unroll
        for (int b = 0; b < 4; ++b)
            #pragma unroll
            for (int jj = 0; jj < 4; ++jj)
                u16[unit * 128 + ksl * 16 + b * 4 + jj] = acc[b][jj];
        __syncthreads();
        #pragma unroll
        for (int e = 0; e < 2; ++e) {
            const int task = e * 256 + tid;
            const int unit2 = task >> 4, rem = task & 15;
            float v = 0.f;
            #pragma unroll
            for (int k2 = 0; k2 < 8; ++k2) v += u16[unit2 * 128 + k2 * 16 + rem];
            const int s2 = unit2 >> 3, jg2 = unit2 & 7;
            const int bb = rem >> 2, jj = rem & 3, j = jg2 * 4 + jj;
            float bias = (s2 < 3) ? (b_ioux[s2 * Mn + m0 + j] + b_iouh[s2 * Mn + m0 + j])
                                  : b_fx[m0 + j];
            s_iouf[(s2 * 4 + bb) * 32 + j] = v + bias;
        }
    }
    __syncthreads();

    {
        const int pos = tid >> 2, ksc = tid & 3, rg = pos >> 3, jg = pos & 7;
        float acc[4][4];
        #pragma unroll
        for (int r = 0; r < 4; ++r)
            #pragma unroll
            for (int j = 0; j < 4; ++j) acc[r][j] = 0.f;
        #pragma unroll 4
        for (int it = 0; it < 32; ++it) {
            const int k = it * 16 + ksc * 4;
            float4 ch[4], wf[4];
            #pragma unroll
            for (int r = 0; r < 4; ++r) ch[r] = *(const float4*)&s_ch[(rg * 4 + r) * LDK + k];
            #pragma unroll
            for (int j = 0; j < 4; ++j) wf[j] = *(const float4*)&s_wfh[(jg * 4 + j) * LDK + k];
            #pragma unroll
            for (int r = 0; r < 4; ++r)
                #pragma unroll
                for (int j = 0; j < 4; ++j) acc[r][j] += dot4_(ch[r], wf[j]);
        }
        #pragma unroll
        for (int r = 0; r < 4; ++r)
            #pragma unroll
            for (int j = 0; j < 4; ++j)
                u16[((rg * 4 + r) * 32 + (jg * 4 + j)) * 4 + ksc] = acc[r][j];
    }
    __syncthreads();

    if (tid < 128) {
        const int b = tid >> 5, j = tid & 31;
        const float iv  = s_iouf[(0 * 4 + b) * 32 + j];
        const float ov  = s_iouf[(1 * 4 + b) * 32 + j];
        const float uv  = s_iouf[(2 * 4 + b) * 32 + j];
        const float fxv = s_iouf[(3 * 4 + b) * 32 + j];
        const float i_ = sigmoidf_(iv), o_ = sigmoidf_(ov), u_ = tanhf(uv);
        const float bfh = b_fh[m0 + j];
        float facc = 0.f;
        #pragma unroll
        for (int c = 0; c < 8; ++c) {
            const int row = b * 8 + c;
            const float fd = u16[(row * 32 + j) * 4 + 0] + u16[(row * 32 + j) * 4 + 1]
                           + u16[(row * 32 + j) * 4 + 2] + u16[(row * 32 + j) * 4 + 3];
            const float f = sigmoidf_(fd + bfh + fxv);
            facc += f * s_cs[row * 32 + j] * s_xmc[row];
        }
        const float cval = i_ * u_ + facc;
        const float hval = o_ * tanhf(cval);
        const float mval = s_xm[b];
        const size_t base  = ((size_t)(b0 + b) * Ln + t) * TWO_M;
        const size_t pbase = ((size_t)(b0 + b) * Ln + (t - 1)) * TWO_M;
        out[base + m0 + j]      = mval * cval + (1.f - mval) * out[pbase + m0 + j];
        out[base + Mn + m0 + j] = mval * hval + (1.f - mval) * out[pbase + Mn + m0 + j];
    }
}

__global__ void zero_row0(float* __restrict__ out) {
    int i = blockIdx.x * 256 + threadIdx.x;
    int b = i >> 10, j = i & 1023;
    out[(size_t)b * Ln * TWO_M + j] = 0.f;
}

__global__ void zero_ctr(unsigned* __restrict__ c) {
    if (threadIdx.x < 8) c[threadIdx.x * 32] = 0u;
}

__global__ void final_copy(const float* __restrict__ out, float* __restrict__ fin) {
    int i = blockIdx.x * 256 + threadIdx.x;
    int b = i >> 10, j = i & 1023;
    fin[i] = out[((size_t)b * Ln + (Ln - 1)) * TWO_M + j];
}

} // namespace

extern "C" void kernel_launch(void* const* d_in, const int* in_sizes, int n_in,
                              void* d_out, int out_size, void* d_ws, size_t ws_size,
                              hipStream_t stream) {
    (void)in_sizes; (void)n_in; (void)out_size;
    const float* x      = (const float*)d_in[0];
    const int*   x_c    = (const int*)d_in[1];
    const float* x_m    = (const float*)d_in[2];
    const float* x_m_c  = (const float*)d_in[3];
    const float* W_ioux = (const float*)d_in[4];
    const float* b_ioux = (const float*)d_in[5];
    const float* W_iouh = (const float*)d_in[6];
    const float* b_iouh = (const float*)d_in[7];
    const float* W_fx   = (const float*)d_in[8];
    const float* b_fx   = (const float*)d_in[9];
    const float* W_fh   = (const float*)d_in[10];
    const float* b_fh   = (const float*)d_in[11];
    float* out = (float*)d_out;
    float* fin = out + (size_t)Bn * Ln * TWO_M;

    hipFuncSetAttribute((const void*)persist8_kernel,
                        hipFuncAttributeMaxDynamicSharedMemorySize, (int)R_LDS_BYTES);
    hipFuncSetAttribute((const void*)step_legacy,
                        hipFuncAttributeMaxDynamicSharedMemorySize, (int)L_BYTES);

    hipLaunchKernelGGL(zero_row0, dim3(256), dim3(256), 0, stream, out);

    if (ws_size >= P_BYTES) {
        float* Pp = (float*)d_ws;
        // barrier counters overlap P row (b=0,t=0), which no step reads.
        unsigned* ctr = (unsigned*)d_ws;
        hipLaunchKernelGGL(proj2_kernel, dim3(8192), dim3(256), 0, stream,
                           x, W_ioux, b_ioux, b_iouh, W_fx, b_fx, Pp);
        hipLaunchKernelGGL(zero_ctr, dim3(1), dim3(64), 0, stream, ctr);
        void* kargs[] = { (void*)&x_c, (void*)&x_m, (void*)&x_m_c, (void*)&W_iouh,
                          (void*)&W_fh, (void*)&b_fh, (void*)&Pp, (void*)&out,
                          (void*)&ctr };
        hipLaunchCooperativeKernel((const void*)persist8_kernel, dim3(256), dim3(512),
                                   kargs, (unsigned)R_LDS_BYTES, stream);
    } else {
        for (int t = 1; t < Ln; ++t) {
            hipLaunchKernelGGL(step_legacy, dim3(256), dim3(256), L_BYTES, stream,
                               x, x_c, x_m, x_m_c, W_ioux, b_ioux, W_iouh, b_iouh,
                               W_fx, b_fx, W_fh, b_fh, out, t);
        }
    }
    hipLaunchKernelGGL(final_copy, dim3(256), dim3(256), 0, stream, out, fin);
}

// Round 11
// 5424.925 us; speedup vs baseline: 1.0603x; 1.0603x over previous
//
#include <hip/hip_runtime.h>
#include <math.h>

namespace {

constexpr int Bn = 64, Ln = 256, Cn = 8, Dn = 512, Mn = 512;
constexpr int TWO_M = 2 * Mn;        // 1024
constexpr int PCOLS = 2048;          // 1536 iou (+both biases) | 512 fx (+b_fx)
constexpr size_t P_FLOATS = (size_t)Bn * Ln * PCOLS;   // 33,554,432
constexpr size_t P_BYTES  = P_FLOATS * 4;              // 128 MB

__device__ __forceinline__ float sigmoidf_(float v) { return 1.0f / (1.0f + __expf(-v)); }
__device__ __forceinline__ float dot4_(float4 a, float4 b) {
    return a.x * b.x + a.y * b.y + a.z * b.z + a.w * b.w;
}

// ============================================================================
// proj2: P[r][0:1536] = x_r @ W_ioux.T + b_ioux + b_iouh
//        P[r][1536:2048] = x_r @ W_fx.T + b_fx        (r = b*Ln + t)
// ============================================================================
constexpr int PJLD = 36;

__global__ __launch_bounds__(256)
void proj2_kernel(const float* __restrict__ x,
                  const float* __restrict__ W_ioux, const float* __restrict__ b_ioux,
                  const float* __restrict__ b_iouh,
                  const float* __restrict__ W_fx, const float* __restrict__ b_fx,
                  float* __restrict__ P)
{
    __shared__ float sA[64 * PJLD];
    __shared__ float sB[64 * PJLD];
    const int tid = threadIdx.x;
    const int rb = blockIdx.x >> 5;       // 0..255
    const int cb = blockIdx.x & 31;       // 0..31
    const int r0 = rb * 64, c0 = cb * 64;
    const bool is_iou = (c0 < 3 * Mn);
    const int ri = tid & 15, ci = tid >> 4;

    float acc[4][4];
    #pragma unroll
    for (int r = 0; r < 4; ++r)
        #pragma unroll
        for (int c = 0; c < 4; ++c) acc[r][c] = 0.f;

    for (int k0 = 0; k0 < Dn; k0 += 32) {
        #pragma unroll
        for (int i = 0; i < 2; ++i) {
            const int flat = i * 256 + tid;           // 0..511
            const int row = flat >> 3, kq = flat & 7;
            *(float4*)&sA[row * PJLD + kq * 4] =
                *(const float4*)&x[(size_t)(r0 + row) * Dn + k0 + kq * 4];
            const float* wsrc = is_iou ? &W_ioux[(size_t)(c0 + row) * Dn]
                                       : &W_fx[(size_t)(c0 - 3 * Mn + row) * Dn];
            *(float4*)&sB[row * PJLD + kq * 4] = *(const float4*)&wsrc[k0 + kq * 4];
        }
        __syncthreads();
        #pragma unroll
        for (int k4 = 0; k4 < 8; ++k4) {
            float4 av[4], bv[4];
            #pragma unroll
            for (int r = 0; r < 4; ++r) av[r] = *(const float4*)&sA[(ri + r * 16) * PJLD + k4 * 4];
            #pragma unroll
            for (int c = 0; c < 4; ++c) bv[c] = *(const float4*)&sB[(ci + c * 16) * PJLD + k4 * 4];
            #pragma unroll
            for (int r = 0; r < 4; ++r)
                #pragma unroll
                for (int c = 0; c < 4; ++c) acc[r][c] += dot4_(av[r], bv[c]);
        }
        __syncthreads();
    }
    #pragma unroll
    for (int c = 0; c < 4; ++c) {
        const int col = c0 + ci + c * 16;
        const float bias = is_iou ? (b_ioux[col] + b_iouh[col]) : b_fx[col - 3 * Mn];
        #pragma unroll
        for (int r = 0; r < 4; ++r)
            P[(size_t)(r0 + ri + r * 16) * PCOLS + col] = acc[r][c] + bias;
    }
}

// ============================================================================
// persist9: persist7 (proven best) with ONE change — G2 re-tiled to
// 4 rows x 8 cols x ks16 (acc[4][8]) so gather redundancy drops 4->2
// (cv loads per thread 64->32; block gather traffic 644->388 KB/step).
// wv LDS reads unchanged via re-derived conflict-free w2 layout.
// 256 blocks = 8 groups (bid&7, XCD-co-located) x 32 m-blocks.
// ============================================================================
// LDS carve (floats)
constexpr int R_W2  = 0;                  // W_fh slice:  f4[(i*8+jj)*32+lane]  = 8192
constexpr int R_W1  = R_W2 + 8192;        // W_iouh slice: f4[(i*2+cc)*192+..]  = 24576
constexpr int R_HS  = R_W1 + 24576;       // h_sum 8x512  = 4096
constexpr int R_FD  = R_HS + 4096;        // G2 out 64x16 = 1024
constexpr int R_IO  = R_FD + 1024;        // G1 out 8x48  = 384
constexpr int R_CS  = R_IO + 384;         // c_s 64x16    = 1024
constexpr int R_PV  = R_CS + 1024;        // prev 8x32    = 256
constexpr int R_XMC = R_PV + 256;         // 64
constexpr int R_XM  = R_XMC + 64;         // 8
constexpr int R_RB  = R_XM + 8;           // 64 ints (row elt offsets, row0-redirected)
constexpr int R_FLOATS = R_RB + 64;       // 39688
constexpr size_t R_LDS_BYTES = (size_t)R_FLOATS * 4;   // 158,752 B
static_assert(R_LDS_BYTES <= 163840, "persist9 LDS over budget");

__global__ __launch_bounds__(512, 1)
void persist9_kernel(const int* __restrict__ x_c, const float* __restrict__ x_m,
                     const float* __restrict__ x_m_c,
                     const float* __restrict__ W_iouh, const float* __restrict__ W_fh,
                     const float* __restrict__ b_fh, const float* __restrict__ P,
                     float* __restrict__ out, unsigned* __restrict__ ctr)
{
    extern __shared__ float lds[];
    float* w2   = lds + R_W2;
    float* w1   = lds + R_W1;
    float* s_hs = lds + R_HS;
    float* s_fd = lds + R_FD;
    float* s_io = lds + R_IO;
    float* s_cs = lds + R_CS;
    float* s_pv = lds + R_PV;
    float* s_xmc = lds + R_XMC;
    float* s_xm  = lds + R_XM;
    int*   s_rb  = (int*)(lds + R_RB);

    const int tid = threadIdx.x;
    const int g  = blockIdx.x & 7;        // group varies fastest -> XCD co-location
    const int mt = blockIdx.x >> 3;       // 0..31
    const int m0 = mt * 16;
    const int b0 = g * 8;
    unsigned* myctr = ctr + g * 32;       // 128B-separated counters

    // ---- one-time: W_fh slice -> LDS, f4 q=(i*8+jj)*32 + jh*16 + ks ----
    // holds W_fh col (jh*8+jj), floats [ks*4 + i*64 .. +3]; per-(i,jj) read is
    // 32 consecutive f4 (512B) across the 32-lane group -> conflict-free.
    #pragma unroll
    for (int chk = 0; chk < 4; ++chk) {
        const int q = chk * 512 + tid;            // f4 id 0..2047
        const int i = q >> 8, r = q & 255;
        const int jj = r >> 5, l = r & 31;
        const int jh = l >> 4, ks = l & 15;
        *(float4*)&w2[q * 4] =
            *(const float4*)&W_fh[(size_t)(m0 + jh * 8 + jj) * Dn + ks * 4 + i * 64];
    }
    // ---- one-time: W_iouh slice -> LDS, lane-linear f4[(i*2+cc)*192 + cq*8+ks] ----
    #pragma unroll
    for (int chk = 0; chk < 12; ++chk) {
        const int q = chk * 512 + tid;            // f4 id 0..6143
        const int i = q / 384, r1 = q % 384;
        const int cc = r1 / 192, lane192 = r1 % 192;
        const int cq = lane192 >> 3, ks = lane192 & 7;
        const int col = cq * 2 + cc, s = col >> 4, j = col & 15;
        *(float4*)&w1[q * 4] =
            *(const float4*)&W_iouh[(size_t)(s * Mn + m0 + j) * Mn + ks * 4 + i * 32];
    }

    // thread mappings
    const int g2_ks = tid & 15, g2_jh = (tid >> 4) & 1, g2_rq = tid >> 5;  // 16 rq x 2 jh x 16 ks
    const int g2_l  = tid & 31;                                            // lane within 32-group
    const int g1_bq = tid / 192, g1_r = tid % 192;
    const int g1_cq = g1_r >> 3, g1_ks = g1_r & 7;                         // 2 bq x 24 cq x 8 ks
    const int p1_b = tid >> 6, p1_k = tid & 63;

    const float bfh_j = b_fh[m0 + (tid & 15)];
    if (tid < 256) s_pv[tid] = 0.f;

    // ---- preload step t=1 scalars + P into registers ----
    int   sc_idx = 0;  float sc_xmc = 0.f, sc_xm = 0.f;
    float p0 = 0.f, p1 = 0.f, p2 = 0.f, p3 = 0.f;
    if (tid < 64) {
        const int b = tid >> 3, c = tid & 7;
        sc_idx = x_c[((size_t)(b0 + b) * Ln + 1) * Cn + c];
        sc_xmc = x_m_c[((size_t)(b0 + b) * Ln + 1) * Cn + c];
    } else if (tid < 72) {
        sc_xm = x_m[(size_t)(b0 + tid - 64) * Ln + 1];
    }
    if (tid < 128) {
        const size_t prow = ((size_t)(b0 + (tid >> 4)) * Ln + 1) * (size_t)PCOLS
                            + m0 + (tid & 15);
        p0 = P[prow];           p1 = P[prow + Mn];
        p2 = P[prow + 2 * Mn];  p3 = P[prow + 3 * Mn];
    }
    __syncthreads();

    for (int t = 1; t < Ln; ++t) {
        // ---- commit scalars; invalid children redirect to zeroed row 0 ----
        if (tid < 64) {
            const int ci = (sc_idx < t) ? sc_idx : 0;
            s_xmc[tid] = sc_xmc;
            s_rb[tid]  = ((b0 + (tid >> 3)) * Ln + ci) * TWO_M;
        } else if (tid < 72) {
            s_xm[tid - 64] = sc_xm;
        }
        __syncthreads();

        // ---- pass1: h_sum (wave = one batch, contiguous k, unguarded loads) ----
        {
            const float* rowp[8];
            float wt[8];
            #pragma unroll
            for (int c = 0; c < 8; ++c) {
                rowp[c] = &out[(size_t)s_rb[p1_b * 8 + c] + Mn];
                wt[c]   = s_xmc[p1_b * 8 + c];
            }
            #pragma unroll
            for (int i = 0; i < 2; ++i) {
                const int k = p1_k * 4 + i * 256;
                float4 hs = make_float4(0.f, 0.f, 0.f, 0.f);
                #pragma unroll
                for (int c = 0; c < 8; ++c) {
                    const float4 v = *(const float4*)&rowp[c][k];
                    hs.x += wt[c] * v.x; hs.y += wt[c] * v.y;
                    hs.z += wt[c] * v.z; hs.w += wt[c] * v.w;
                }
                *(float4*)&s_hs[p1_b * 512 + k] = hs;
            }
        }
        // ---- c_s gather (own 16 cols, unguarded) ----
        if (tid < 256) {
            const int row = tid >> 2, q = tid & 3;
            const float4 v = *(const float4*)&out[(size_t)s_rb[row] + m0 + q * 4];
            *(float4*)&s_cs[row * 16 + q * 4] = v;
        }

        // ---- G2: c_h(64x512) @ W_fh.T(16); 4 rows x 8 cols x ks16 ----
        {
            const float* rp[4];
            #pragma unroll
            for (int r = 0; r < 4; ++r)
                rp[r] = &out[(size_t)s_rb[g2_rq * 4 + r] + Mn];
            float acc[4][8];
            #pragma unroll
            for (int r = 0; r < 4; ++r)
                #pragma unroll
                for (int jj = 0; jj < 8; ++jj) acc[r][jj] = 0.f;
            #pragma unroll 2
            for (int i = 0; i < 8; ++i) {
                const int k = g2_ks * 4 + i * 64;
                float4 cv[4];
                #pragma unroll
                for (int r = 0; r < 4; ++r) cv[r] = *(const float4*)&rp[r][k];
                #pragma unroll
                for (int jj = 0; jj < 8; ++jj) {
                    const float4 wv = *(const float4*)&w2[((i * 8 + jj) * 32 + g2_l) * 4];
                    #pragma unroll
                    for (int r = 0; r < 4; ++r) acc[r][jj] += dot4_(cv[r], wv);
                }
            }
            #pragma unroll
            for (int r = 0; r < 4; ++r)
                #pragma unroll
                for (int jj = 0; jj < 8; ++jj) {
                    float v = acc[r][jj];
                    v += __shfl_xor(v, 1); v += __shfl_xor(v, 2);
                    v += __shfl_xor(v, 4); v += __shfl_xor(v, 8);
                    acc[r][jj] = v;
                }
            if (g2_ks == 0) {
                #pragma unroll
                for (int r = 0; r < 4; ++r) {
                    *(float4*)&s_fd[(g2_rq * 4 + r) * 16 + g2_jh * 8] =
                        make_float4(acc[r][0], acc[r][1], acc[r][2], acc[r][3]);
                    *(float4*)&s_fd[(g2_rq * 4 + r) * 16 + g2_jh * 8 + 4] =
                        make_float4(acc[r][4], acc[r][5], acc[r][6], acc[r][7]);
                }
            }
        }
        __syncthreads();   // s_hs ready for G1; s_fd/s_cs ready for gates

        // ---- G1: h_sum(8x512) @ W_iouh.T(48); 4 b x 2 cols x ks8 ----
        if (tid < 384) {
            float acc[2][4];
            #pragma unroll
            for (int cc = 0; cc < 2; ++cc)
                #pragma unroll
                for (int bb = 0; bb < 4; ++bb) acc[cc][bb] = 0.f;
            #pragma unroll 4
            for (int i = 0; i < 16; ++i) {
                const int k = g1_ks * 4 + i * 32;
                float4 hv[4];
                #pragma unroll
                for (int bb = 0; bb < 4; ++bb)
                    hv[bb] = *(const float4*)&s_hs[(g1_bq * 4 + bb) * 512 + k];
                #pragma unroll
                for (int cc = 0; cc < 2; ++cc) {
                    const float4 wv = *(const float4*)&w1[((i * 2 + cc) * 192
                                                           + g1_cq * 8 + g1_ks) * 4];
                    #pragma unroll
                    for (int bb = 0; bb < 4; ++bb) acc[cc][bb] += dot4_(hv[bb], wv);
                }
            }
            #pragma unroll
            for (int cc = 0; cc < 2; ++cc)
                #pragma unroll
                for (int bb = 0; bb < 4; ++bb) {
                    float v = acc[cc][bb];
                    v += __shfl_xor(v, 1); v += __shfl_xor(v, 2); v += __shfl_xor(v, 4);
                    acc[cc][bb] = v;
                }
            if (g1_ks == 0) {
                #pragma unroll
                for (int cc = 0; cc < 2; ++cc)
                    #pragma unroll
                    for (int bb = 0; bb < 4; ++bb)
                        s_io[(g1_bq * 4 + bb) * 48 + g1_cq * 2 + cc] = acc[cc][bb];
            }
        }

        // ---- prefetch next-step scalars + P (hidden under G1/gates/barrier) ----
        int   nx_idx = 0;  float nx_xmc = 0.f, nx_xm = 0.f;
        float np0 = 0.f, np1 = 0.f, np2 = 0.f, np3 = 0.f;
        if (t < Ln - 1) {
            const int tn = t + 1;
            if (tid < 64) {
                const int b = tid >> 3, c = tid & 7;
                nx_idx = x_c[((size_t)(b0 + b) * Ln + tn) * Cn + c];
                nx_xmc = x_m_c[((size_t)(b0 + b) * Ln + tn) * Cn + c];
            } else if (tid < 72) {
                nx_xm = x_m[(size_t)(b0 + tid - 64) * Ln + tn];
            }
            if (tid < 128) {
                const size_t prow = ((size_t)(b0 + (tid >> 4)) * Ln + tn) * (size_t)PCOLS
                                    + m0 + (tid & 15);
                np0 = P[prow];           np1 = P[prow + Mn];
                np2 = P[prow + 2 * Mn];  np3 = P[prow + 3 * Mn];
            }
        }
        __syncthreads();   // s_io ready for gates

        // ---- gates, c/h, blend vs s_pv, store ----
        if (tid < 128) {
            const int b = tid >> 4, j = tid & 15;
            const float iv = s_io[b * 48 + j]      + p0;
            const float ov = s_io[b * 48 + 16 + j] + p1;
            const float uv = s_io[b * 48 + 32 + j] + p2;
            const float i_ = sigmoidf_(iv);
            const float o_ = sigmoidf_(ov);
            const float u_ = tanhf(uv);
            float facc = 0.f;
            #pragma unroll
            for (int c = 0; c < 8; ++c) {
                const int row = b * 8 + c;
                const float f = sigmoidf_(s_fd[row * 16 + j] + bfh_j + p3);
                facc += f * s_cs[row * 16 + j] * s_xmc[row];
            }
            const float cv = i_ * u_ + facc;
            const float hv = o_ * tanhf(cv);
            const float mv = s_xm[b];
            const float nc = mv * cv + (1.f - mv) * s_pv[b * 32 + j];
            const float nh = mv * hv + (1.f - mv) * s_pv[b * 32 + 16 + j];
            const size_t ob = ((size_t)(b0 + b) * Ln + t) * TWO_M;
            out[ob + m0 + j]      = nc;
            out[ob + Mn + m0 + j] = nh;
            s_pv[b * 32 + j]      = nc;
            s_pv[b * 32 + 16 + j] = nh;
        }
        __syncthreads();

        // ---- group barrier (release writes / acquire before next gather) ----
        if (t < Ln - 1) {
            if (tid == 0) {
                __hip_atomic_fetch_add(myctr, 1u, __ATOMIC_RELEASE, __HIP_MEMORY_SCOPE_AGENT);
                const unsigned target = 32u * (unsigned)t;
                while (__hip_atomic_load(myctr, __ATOMIC_RELAXED, __HIP_MEMORY_SCOPE_AGENT) < target)
                    __builtin_amdgcn_s_sleep(2);
                (void)__hip_atomic_load(myctr, __ATOMIC_ACQUIRE, __HIP_MEMORY_SCOPE_AGENT);
            }
            __syncthreads();
        }
        // rotate prefetched registers
        sc_idx = nx_idx; sc_xmc = nx_xmc; sc_xm = nx_xm;
        p0 = np0; p1 = np1; p2 = np2; p3 = np3;
    }
}

// ============================================================================
// Legacy monolithic step kernel (fallback when ws is too small for P)
// ============================================================================
constexpr int LBT = 4, LMT = 32, LNMT = Mn / LMT, LPAD = 4, LDK = Dn + LPAD;
constexpr int L_U16 = 4096, L_CHS = LBT * LDK, L_CH = LBT * Cn * LDK,
              L_WFH = LMT * LDK, L_CS = LBT * Cn * LMT, L_IOUF = 4 * LBT * LMT;
constexpr int L_FLOATS = L_U16 + L_CHS + L_CH + L_WFH + L_CS + L_IOUF + 32 + 4 + 32;
constexpr size_t L_BYTES = (size_t)L_FLOATS * 4;

__global__ __launch_bounds__(256, 1)
void step_legacy(const float* __restrict__ x, const int* __restrict__ x_c,
                 const float* __restrict__ x_m, const float* __restrict__ x_m_c,
                 const float* __restrict__ W_ioux, const float* __restrict__ b_ioux,
                 const float* __restrict__ W_iouh, const float* __restrict__ b_iouh,
                 const float* __restrict__ W_fx, const float* __restrict__ b_fx,
                 const float* __restrict__ W_fh, const float* __restrict__ b_fh,
                 float* __restrict__ out, int t)
{
    extern __shared__ float lds[];
    float* u16    = lds;
    float* s_chs  = u16 + L_U16;
    float* s_ch   = s_chs + L_CHS;
    float* s_wfh  = s_ch + L_CH;
    float* s_cs   = s_wfh + L_WFH;
    float* s_iouf = s_cs + L_CS;
    float* s_xmc  = s_iouf + L_IOUF;
    float* s_xm   = s_xmc + 32;
    int*   s_xc   = (int*)(s_xm + 4);

    const int tid = threadIdx.x;
    const int mt = blockIdx.x & (LNMT - 1);
    const int bt = blockIdx.x >> 4;
    const int b0 = bt * LBT, m0 = mt * LMT;

    #pragma unroll
    for (int i = 0; i < 8; ++i) {
        int flat = i * 256 + tid, b = flat >> 9, k = flat & 511;
        u16[b * LDK + k] = x[((size_t)(b0 + b) * Ln + t) * Dn + k];
    }
    if (tid < 32) {
        int b = tid >> 3, c = tid & 7;
        s_xc[tid]  = x_c[((size_t)(b0 + b) * Ln + t) * Cn + c];
        s_xmc[tid] = x_m_c[((size_t)(b0 + b) * Ln + t) * Cn + c];
    }
    if (tid < 4) s_xm[tid] = x_m[(size_t)(b0 + tid) * Ln + t];
    for (int i = 0; i < 64; ++i) {
        int flat = i * 256 + tid, j = flat >> 9, k = flat & 511;
        s_wfh[j * LDK + k] = W_fh[(size_t)(m0 + j) * Dn + k];
    }
    __syncthreads();

    #pragma unroll
    for (int i = 0; i < 8; ++i) {
        int flat = i * 256 + tid, b = flat >> 9, k = flat & 511;
        float acc = 0.f;
        #pragma unroll
        for (int c = 0; c < 8; ++c) {
            int idx = s_xc[b * 8 + c];
            float v = 0.f;
            if (idx < t) v = out[((size_t)(b0 + b) * Ln + idx) * TWO_M + Mn + k];
            s_ch[(b * 8 + c) * LDK + k] = v;
            acc += s_xmc[b * 8 + c] * v;
        }
        s_chs[b * LDK + k] = acc;
    }
    #pragma unroll
    for (int i = 0; i < 4; ++i) {
        int flat = i * 256 + tid;
        int b = flat >> 8, rem = flat & 255, c = rem >> 5, j = rem & 31;
        int idx = s_xc[b * 8 + c];
        float v = 0.f;
        if (idx < t) v = out[((size_t)(b0 + b) * Ln + idx) * TWO_M + m0 + j];
        s_cs[flat] = v;
    }
    __syncthreads();

    {
        const int unit = tid >> 3, ksl = tid & 7, s = unit >> 3, jg = unit & 7;
        float acc[4][4];
        #pragma unroll
        for (int b = 0; b < 4; ++b)
            #pragma unroll
            for (int jj = 0; jj < 4; ++jj) acc[b][jj] = 0.f;
        if (s < 3) {
            const int colbase = s * Mn + m0 + jg * 4;
            #pragma unroll 4
            for (int it = 0; it < 16; ++it) {
                const int k = it * 32 + ksl * 4;
                float4 sx[4], sc[4];
                #pragma unroll
                for (int b = 0; b < 4; ++b) {
                    sx[b] = *(const float4*)&u16[b * LDK + k];
                    sc[b] = *(const float4*)&s_chs[b * LDK + k];
                }
                #pragma unroll
                for (int jj = 0; jj < 4; ++jj) {
                    const float4 wx = *(const float4*)&W_ioux[(size_t)(colbase + jj) * Dn + k];
                    const float4 wh = *(const float4*)&W_iouh[(size_t)(colbase + jj) * Dn + k];
                    #pragma unroll
                    for (int b = 0; b < 4; ++b)
                        acc[b][jj] += dot4_(sx[b], wx) + dot4_(sc[b], wh);
                }
            }
        } else {
            const int colbase = m0 + jg * 4;
            #pragma unroll 4
            for (int it = 0; it < 16; ++it) {
                const int k = it * 32 + ksl * 4;
                float4 sx[4];
                #pragma unroll
                for (int b = 0; b < 4; ++b) sx[b] = *(const float4*)&u16[b * LDK + k];
                #pragma unroll
                for (int jj = 0; jj < 4; ++jj) {
                    const float4 wx = *(const float4*)&W_fx[(size_t)(colbase + jj) * Dn + k];
                    #pragma unroll
                    for (int b = 0; b < 4; ++b) acc[b][jj] += dot4_(sx[b], wx);
                }
            }
        }
        __syncthreads();
        #pragma unroll
        for (int b = 0; b < 4; ++b)
            #pragma unroll
            for (int jj = 0; jj < 4; ++jj)
                u16[unit * 128 + ksl * 16 + b * 4 + jj] = acc[b][jj];
        __syncthreads();
        #pragma unroll
        for (int e = 0; e < 2; ++e) {
            const int task = e * 256 + tid;
            const int unit2 = task >> 4, rem = task & 15;
            float v = 0.f;
            #pragma unroll
            for (int k2 = 0; k2 < 8; ++k2) v += u16[unit2 * 128 + k2 * 16 + rem];
            const int s2 = unit2 >> 3, jg2 = unit2 & 7;
            const int bb = rem >> 2, jj = rem & 3, j = jg2 * 4 + jj;
            float bias = (s2 < 3) ? (b_ioux[s2 * Mn + m0 + j] + b_iouh[s2 * Mn + m0 + j])
                                  : b_fx[m0 + j];
            s_iouf[(s2 * 4 + bb) * 32 + j] = v + bias;
        }
    }
    __syncthreads();

    {
        const int pos = tid >> 2, ksc = tid & 3, rg = pos >> 3, jg = pos & 7;
        float acc[4][4];
        #pragma unroll
        for (int r = 0; r < 4; ++r)
            #pragma unroll
            for (int j = 0; j < 4; ++j) acc[r][j] = 0.f;
        #pragma unroll 4
        for (int it = 0; it < 32; ++it) {
            const int k = it * 16 + ksc * 4;
            float4 ch[4], wf[4];
            #pragma unroll
            for (int r = 0; r < 4; ++r) ch[r] = *(const float4*)&s_ch[(rg * 4 + r) * LDK + k];
            #pragma unroll
            for (int j = 0; j < 4; ++j) wf[j] = *(const float4*)&s_wfh[(jg * 4 + j) * LDK + k];
            #pragma unroll
            for (int r = 0; r < 4; ++r)
                #pragma unroll
                for (int j = 0; j < 4; ++j) acc[r][j] += dot4_(ch[r], wf[j]);
        }
        #pragma unroll
        for (int r = 0; r < 4; ++r)
            #pragma unroll
            for (int j = 0; j < 4; ++j)
                u16[((rg * 4 + r) * 32 + (jg * 4 + j)) * 4 + ksc] = acc[r][j];
    }
    __syncthreads();

    if (tid < 128) {
        const int b = tid >> 5, j = tid & 31;
        const float iv  = s_iouf[(0 * 4 + b) * 32 + j];
        const float ov  = s_iouf[(1 * 4 + b) * 32 + j];
        const float uv  = s_iouf[(2 * 4 + b) * 32 + j];
        const float fxv = s_iouf[(3 * 4 + b) * 32 + j];
        const float i_ = sigmoidf_(iv), o_ = sigmoidf_(ov), u_ = tanhf(uv);
        const float bfh = b_fh[m0 + j];
        float facc = 0.f;
        #pragma unroll
        for (int c = 0; c < 8; ++c) {
            const int row = b * 8 + c;
            const float fd = u16[(row * 32 + j) * 4 + 0] + u16[(row * 32 + j) * 4 + 1]
                           + u16[(row * 32 + j) * 4 + 2] + u16[(row * 32 + j) * 4 + 3];
            const float f = sigmoidf_(fd + bfh + fxv);
            facc += f * s_cs[row * 32 + j] * s_xmc[row];
        }
        const float cval = i_ * u_ + facc;
        const float hval = o_ * tanhf(cval);
        const float mval = s_xm[b];
        const size_t base  = ((size_t)(b0 + b) * Ln + t) * TWO_M;
        const size_t pbase = ((size_t)(b0 + b) * Ln + (t - 1)) * TWO_M;
        out[base + m0 + j]      = mval * cval + (1.f - mval) * out[pbase + m0 + j];
        out[base + Mn + m0 + j] = mval * hval + (1.f - mval) * out[pbase + Mn + m0 + j];
    }
}

__global__ void zero_row0(float* __restrict__ out) {
    int i = blockIdx.x * 256 + threadIdx.x;
    int b = i >> 10, j = i & 1023;
    out[(size_t)b * Ln * TWO_M + j] = 0.f;
}

__global__ void zero_ctr(unsigned* __restrict__ c) {
    if (threadIdx.x < 8) c[threadIdx.x * 32] = 0u;
}

__global__ void final_copy(const float* __restrict__ out, float* __restrict__ fin) {
    int i = blockIdx.x * 256 + threadIdx.x;
    int b = i >> 10, j = i & 1023;
    fin[i] = out[((size_t)b * Ln + (Ln - 1)) * TWO_M + j];
}

} // namespace

extern "C" void kernel_launch(void* const* d_in, const int* in_sizes, int n_in,
                              void* d_out, int out_size, void* d_ws, size_t ws_size,
                              hipStream_t stream) {
    (void)in_sizes; (void)n_in; (void)out_size;
    const float* x      = (const float*)d_in[0];
    const int*   x_c    = (const int*)d_in[1];
    const float* x_m    = (const float*)d_in[2];
    const float* x_m_c  = (const float*)d_in[3];
    const float* W_ioux = (const float*)d_in[4];
    const float* b_ioux = (const float*)d_in[5];
    const float* W_iouh = (const float*)d_in[6];
    const float* b_iouh = (const float*)d_in[7];
    const float* W_fx   = (const float*)d_in[8];
    const float* b_fx   = (const float*)d_in[9];
    const float* W_fh   = (const float*)d_in[10];
    const float* b_fh   = (const float*)d_in[11];
    float* out = (float*)d_out;
    float* fin = out + (size_t)Bn * Ln * TWO_M;

    hipFuncSetAttribute((const void*)persist9_kernel,
                        hipFuncAttributeMaxDynamicSharedMemorySize, (int)R_LDS_BYTES);
    hipFuncSetAttribute((const void*)step_legacy,
                        hipFuncAttributeMaxDynamicSharedMemorySize, (int)L_BYTES);

    hipLaunchKernelGGL(zero_row0, dim3(256), dim3(256), 0, stream, out);

    if (ws_size >= P_BYTES) {
        float* Pp = (float*)d_ws;
        // barrier counters overlap P row (b=0,t=0), which no step reads.
        unsigned* ctr = (unsigned*)d_ws;
        hipLaunchKernelGGL(proj2_kernel, dim3(8192), dim3(256), 0, stream,
                           x, W_ioux, b_ioux, b_iouh, W_fx, b_fx, Pp);
        hipLaunchKernelGGL(zero_ctr, dim3(1), dim3(64), 0, stream, ctr);
        void* kargs[] = { (void*)&x_c, (void*)&x_m, (void*)&x_m_c, (void*)&W_iouh,
                          (void*)&W_fh, (void*)&b_fh, (void*)&Pp, (void*)&out,
                          (void*)&ctr };
        hipLaunchCooperativeKernel((const void*)persist9_kernel, dim3(256), dim3(512),
                                   kargs, (unsigned)R_LDS_BYTES, stream);
    } else {
        for (int t = 1; t < Ln; ++t) {
            hipLaunchKernelGGL(step_legacy, dim3(256), dim3(256), L_BYTES, stream,
                               x, x_c, x_m, x_m_c, W_ioux, b_ioux, W_iouh, b_iouh,
                               W_fx, b_fx, W_fh, b_fh, out, t);
        }
    }
    hipLaunchKernelGGL(final_copy, dim3(256), dim3(256), 0, stream, out, fin);
}

// Round 12
// 4337.225 us; speedup vs baseline: 1.3262x; 1.2508x over previous
//
#include <hip/hip_runtime.h>
#include <math.h>

namespace {

constexpr int Bn = 64, Ln = 256, Cn = 8, Dn = 512, Mn = 512;
constexpr int TWO_M = 2 * Mn;        // 1024
constexpr int PCOLS = 2048;          // 1536 iou (+both biases) | 512 fx (+b_fx)
constexpr size_t P_FLOATS = (size_t)Bn * Ln * PCOLS;   // 33,554,432
constexpr size_t P_BYTES  = P_FLOATS * 4;              // 128 MB

__device__ __forceinline__ float sigmoidf_(float v) { return 1.0f / (1.0f + __expf(-v)); }
__device__ __forceinline__ float dot4_(float4 a, float4 b) {
    return a.x * b.x + a.y * b.y + a.z * b.z + a.w * b.w;
}

// ============================================================================
// proj2: P[r][0:1536] = x_r @ W_ioux.T + b_ioux + b_iouh
//        P[r][1536:2048] = x_r @ W_fx.T + b_fx        (r = b*Ln + t)
// ============================================================================
constexpr int PJLD = 36;

__global__ __launch_bounds__(256)
void proj2_kernel(const float* __restrict__ x,
                  const float* __restrict__ W_ioux, const float* __restrict__ b_ioux,
                  const float* __restrict__ b_iouh,
                  const float* __restrict__ W_fx, const float* __restrict__ b_fx,
                  float* __restrict__ P)
{
    __shared__ float sA[64 * PJLD];
    __shared__ float sB[64 * PJLD];
    const int tid = threadIdx.x;
    const int rb = blockIdx.x >> 5;       // 0..255
    const int cb = blockIdx.x & 31;       // 0..31
    const int r0 = rb * 64, c0 = cb * 64;
    const bool is_iou = (c0 < 3 * Mn);
    const int ri = tid & 15, ci = tid >> 4;

    float acc[4][4];
    #pragma unroll
    for (int r = 0; r < 4; ++r)
        #pragma unroll
        for (int c = 0; c < 4; ++c) acc[r][c] = 0.f;

    for (int k0 = 0; k0 < Dn; k0 += 32) {
        #pragma unroll
        for (int i = 0; i < 2; ++i) {
            const int flat = i * 256 + tid;           // 0..511
            const int row = flat >> 3, kq = flat & 7;
            *(float4*)&sA[row * PJLD + kq * 4] =
                *(const float4*)&x[(size_t)(r0 + row) * Dn + k0 + kq * 4];
            const float* wsrc = is_iou ? &W_ioux[(size_t)(c0 + row) * Dn]
                                       : &W_fx[(size_t)(c0 - 3 * Mn + row) * Dn];
            *(float4*)&sB[row * PJLD + kq * 4] = *(const float4*)&wsrc[k0 + kq * 4];
        }
        __syncthreads();
        #pragma unroll
        for (int k4 = 0; k4 < 8; ++k4) {
            float4 av[4], bv[4];
            #pragma unroll
            for (int r = 0; r < 4; ++r) av[r] = *(const float4*)&sA[(ri + r * 16) * PJLD + k4 * 4];
            #pragma unroll
            for (int c = 0; c < 4; ++c) bv[c] = *(const float4*)&sB[(ci + c * 16) * PJLD + k4 * 4];
            #pragma unroll
            for (int r = 0; r < 4; ++r)
                #pragma unroll
                for (int c = 0; c < 4; ++c) acc[r][c] += dot4_(av[r], bv[c]);
        }
        __syncthreads();
    }
    #pragma unroll
    for (int c = 0; c < 4; ++c) {
        const int col = c0 + ci + c * 16;
        const float bias = is_iou ? (b_ioux[col] + b_iouh[col]) : b_fx[col - 3 * Mn];
        #pragma unroll
        for (int r = 0; r < 4; ++r)
            P[(size_t)(r0 + ri + r * 16) * PCOLS + col] = acc[r][c] + bias;
    }
}

// ============================================================================
// persist10: persist7 (proven best) + CONDITIONAL group barrier.
// Every step every block SIGNALS (release fetch_add, fire-and-forget), but
// only WAITS+ACQUIRES when one of its next-step children points into the
// un-acquired window (last_wait, t]. Skipped steps read only rows covered by
// the last acquire, so no stale data; skipping also avoids the L2 invalidate,
// keeping the gather working set L2-hot.
// 256 blocks = 8 groups (bid&7, XCD-co-located) x 32 m-blocks.
// ============================================================================
// LDS carve (floats)
constexpr int R_W2  = 0;                  // W_fh slice:  f4[i16][jj4][32lane]  = 8192
constexpr int R_W1  = R_W2 + 8192;        // W_iouh slice: f4[(i*2+cc)*192+..]  = 24576
constexpr int R_HS  = R_W1 + 24576;       // h_sum 8x512  = 4096
constexpr int R_FD  = R_HS + 4096;        // G2 out 64x16 = 1024
constexpr int R_IO  = R_FD + 1024;        // G1 out 8x48  = 384
constexpr int R_CS  = R_IO + 384;         // c_s 64x16    = 1024
constexpr int R_PV  = R_CS + 1024;        // prev 8x32    = 256
constexpr int R_XMC = R_PV + 256;         // 64
constexpr int R_XM  = R_XMC + 64;         // 8
constexpr int R_RB  = R_XM + 8;           // 64 ints (row elt offsets, row0-redirected)
constexpr int R_FLOATS = R_RB + 64;       // 39688
constexpr size_t R_LDS_BYTES = (size_t)R_FLOATS * 4;   // 158,752 B
static_assert(R_LDS_BYTES <= 163840, "persist10 LDS over budget");

__global__ __launch_bounds__(512, 1)
void persist10_kernel(const int* __restrict__ x_c, const float* __restrict__ x_m,
                      const float* __restrict__ x_m_c,
                      const float* __restrict__ W_iouh, const float* __restrict__ W_fh,
                      const float* __restrict__ b_fh, const float* __restrict__ P,
                      float* __restrict__ out, unsigned* __restrict__ ctr)
{
    extern __shared__ float lds[];
    float* w2   = lds + R_W2;
    float* w1   = lds + R_W1;
    float* s_hs = lds + R_HS;
    float* s_fd = lds + R_FD;
    float* s_io = lds + R_IO;
    float* s_cs = lds + R_CS;
    float* s_pv = lds + R_PV;
    float* s_xmc = lds + R_XMC;
    float* s_xm  = lds + R_XM;
    int*   s_rb  = (int*)(lds + R_RB);

    const int tid = threadIdx.x;
    const int g  = blockIdx.x & 7;        // group varies fastest -> XCD co-location
    const int mt = blockIdx.x >> 3;       // 0..31
    const int m0 = mt * 16;
    const int b0 = g * 8;
    unsigned* myctr = ctr + g * 32;       // 128B-separated counters

    // ---- one-time: W_fh slice -> LDS, contiguous f4[i*128 + jj*32 + jh*8+ks] ----
    #pragma unroll
    for (int chk = 0; chk < 4; ++chk) {
        const int q = chk * 512 + tid;            // f4 id 0..2047
        const int i = q >> 7, jj = (q >> 5) & 3, lane32 = q & 31;
        const int jh = lane32 >> 3, ks = lane32 & 7;
        *(float4*)&w2[q * 4] =
            *(const float4*)&W_fh[(size_t)(m0 + jh * 4 + jj) * Dn + ks * 4 + i * 32];
    }
    // ---- one-time: W_iouh slice -> LDS, lane-linear f4[(i*2+cc)*192 + cq*8+ks] ----
    #pragma unroll
    for (int chk = 0; chk < 12; ++chk) {
        const int q = chk * 512 + tid;            // f4 id 0..6143
        const int i = q / 384, r1 = q % 384;
        const int cc = r1 / 192, lane192 = r1 % 192;
        const int cq = lane192 >> 3, ks = lane192 & 7;
        const int col = cq * 2 + cc, s = col >> 4, j = col & 15;
        *(float4*)&w1[q * 4] =
            *(const float4*)&W_iouh[(size_t)(s * Mn + m0 + j) * Mn + ks * 4 + i * 32];
    }

    // thread mappings (persist7's)
    const int g2_ks = tid & 7, g2_jh = (tid >> 3) & 3, g2_rq = tid >> 5;   // 16 rq x 4 jh x 8 ks
    const int g1_bq = tid / 192, g1_r = tid % 192;
    const int g1_cq = g1_r >> 3, g1_ks = g1_r & 7;                         // 2 bq x 24 cq x 8 ks
    const int p1_b = tid >> 6, p1_k = tid & 63;

    const float bfh_j = b_fh[m0 + (tid & 15)];
    if (tid < 256) s_pv[tid] = 0.f;

    // ---- preload step t=1 scalars + P into registers ----
    int   sc_idx = 0;  float sc_xmc = 0.f, sc_xm = 0.f;
    float p0 = 0.f, p1 = 0.f, p2 = 0.f, p3 = 0.f;
    if (tid < 64) {
        const int b = tid >> 3, c = tid & 7;
        sc_idx = x_c[((size_t)(b0 + b) * Ln + 1) * Cn + c];
        sc_xmc = x_m_c[((size_t)(b0 + b) * Ln + 1) * Cn + c];
    } else if (tid < 72) {
        sc_xm = x_m[(size_t)(b0 + tid - 64) * Ln + 1];
    }
    if (tid < 128) {
        const size_t prow = ((size_t)(b0 + (tid >> 4)) * Ln + 1) * (size_t)PCOLS
                            + m0 + (tid & 15);
        p0 = P[prow];           p1 = P[prow + Mn];
        p2 = P[prow + 2 * Mn];  p3 = P[prow + 3 * Mn];
    }
    int last_wait = 0;   // rows <= last_wait are visible (row 0 zeroed pre-launch)
    __syncthreads();

    for (int t = 1; t < Ln; ++t) {
        // ---- commit scalars; invalid children redirect to zeroed row 0 ----
        if (tid < 64) {
            const int ci = (sc_idx < t) ? sc_idx : 0;
            s_xmc[tid] = sc_xmc;
            s_rb[tid]  = ((b0 + (tid >> 3)) * Ln + ci) * TWO_M;
        } else if (tid < 72) {
            s_xm[tid - 64] = sc_xm;
        }
        __syncthreads();

        // ---- pass1: h_sum (wave = one batch, contiguous k, unguarded loads) ----
        {
            const float* rowp[8];
            float wt[8];
            #pragma unroll
            for (int c = 0; c < 8; ++c) {
                rowp[c] = &out[(size_t)s_rb[p1_b * 8 + c] + Mn];
                wt[c]   = s_xmc[p1_b * 8 + c];
            }
            #pragma unroll
            for (int i = 0; i < 2; ++i) {
                const int k = p1_k * 4 + i * 256;
                float4 hs = make_float4(0.f, 0.f, 0.f, 0.f);
                #pragma unroll
                for (int c = 0; c < 8; ++c) {
                    const float4 v = *(const float4*)&rowp[c][k];
                    hs.x += wt[c] * v.x; hs.y += wt[c] * v.y;
                    hs.z += wt[c] * v.z; hs.w += wt[c] * v.w;
                }
                *(float4*)&s_hs[p1_b * 512 + k] = hs;
            }
        }
        // ---- c_s gather (own 16 cols, unguarded) ----
        if (tid < 256) {
            const int row = tid >> 2, q = tid & 3;
            const float4 v = *(const float4*)&out[(size_t)s_rb[row] + m0 + q * 4];
            *(float4*)&s_cs[row * 16 + q * 4] = v;
        }

        // ---- G2: c_h(64x512) @ W_fh.T(16); 4 rows x 4 cols x ks8, unguarded ----
        {
            const float* rp[4];
            #pragma unroll
            for (int r = 0; r < 4; ++r)
                rp[r] = &out[(size_t)s_rb[g2_rq * 4 + r] + Mn];
            float acc[4][4];
            #pragma unroll
            for (int r = 0; r < 4; ++r)
                #pragma unroll
                for (int jj = 0; jj < 4; ++jj) acc[r][jj] = 0.f;
            #pragma unroll 4
            for (int i = 0; i < 16; ++i) {
                const int k = g2_ks * 4 + i * 32;
                float4 cv[4], wv[4];
                #pragma unroll
                for (int r = 0; r < 4; ++r) cv[r] = *(const float4*)&rp[r][k];
                #pragma unroll
                for (int jj = 0; jj < 4; ++jj)
                    wv[jj] = *(const float4*)&w2[(i * 128 + jj * 32 + g2_jh * 8 + g2_ks) * 4];
                #pragma unroll
                for (int r = 0; r < 4; ++r)
                    #pragma unroll
                    for (int jj = 0; jj < 4; ++jj) acc[r][jj] += dot4_(cv[r], wv[jj]);
            }
            #pragma unroll
            for (int r = 0; r < 4; ++r)
                #pragma unroll
                for (int jj = 0; jj < 4; ++jj) {
                    float v = acc[r][jj];
                    v += __shfl_xor(v, 1); v += __shfl_xor(v, 2); v += __shfl_xor(v, 4);
                    acc[r][jj] = v;
                }
            if (g2_ks == 0) {
                #pragma unroll
                for (int r = 0; r < 4; ++r)
                    *(float4*)&s_fd[(g2_rq * 4 + r) * 16 + g2_jh * 4] =
                        make_float4(acc[r][0], acc[r][1], acc[r][2], acc[r][3]);
            }
        }
        __syncthreads();   // s_hs ready for G1; s_fd/s_cs ready for gates

        // ---- G1: h_sum(8x512) @ W_iouh.T(48); 4 b x 2 cols x ks8 ----
        if (tid < 384) {
            float acc[2][4];
            #pragma unroll
            for (int cc = 0; cc < 2; ++cc)
                #pragma unroll
                for (int bb = 0; bb < 4; ++bb) acc[cc][bb] = 0.f;
            #pragma unroll 4
            for (int i = 0; i < 16; ++i) {
                const int k = g1_ks * 4 + i * 32;
                float4 hv[4];
                #pragma unroll
                for (int bb = 0; bb < 4; ++bb)
                    hv[bb] = *(const float4*)&s_hs[(g1_bq * 4 + bb) * 512 + k];
                #pragma unroll
                for (int cc = 0; cc < 2; ++cc) {
                    const float4 wv = *(const float4*)&w1[((i * 2 + cc) * 192
                                                           + g1_cq * 8 + g1_ks) * 4];
                    #pragma unroll
                    for (int bb = 0; bb < 4; ++bb) acc[cc][bb] += dot4_(hv[bb], wv);
                }
            }
            #pragma unroll
            for (int cc = 0; cc < 2; ++cc)
                #pragma unroll
                for (int bb = 0; bb < 4; ++bb) {
                    float v = acc[cc][bb];
                    v += __shfl_xor(v, 1); v += __shfl_xor(v, 2); v += __shfl_xor(v, 4);
                    acc[cc][bb] = v;
                }
            if (g1_ks == 0) {
                #pragma unroll
                for (int cc = 0; cc < 2; ++cc)
                    #pragma unroll
                    for (int bb = 0; bb < 4; ++bb)
                        s_io[(g1_bq * 4 + bb) * 48 + g1_cq * 2 + cc] = acc[cc][bb];
            }
        }

        // ---- prefetch next-step scalars + P; compute per-thread "need" ----
        int   nx_idx = 0;  float nx_xmc = 0.f, nx_xm = 0.f;
        float np0 = 0.f, np1 = 0.f, np2 = 0.f, np3 = 0.f;
        int   need = 0;
        if (t < Ln - 1) {
            const int tn = t + 1;
            if (tid < 64) {
                const int b = tid >> 3, c = tid & 7;
                nx_idx = x_c[((size_t)(b0 + b) * Ln + tn) * Cn + c];
                nx_xmc = x_m_c[((size_t)(b0 + b) * Ln + tn) * Cn + c];
                const int eff = (nx_idx < tn) ? nx_idx : 0;   // row used at step t+1
                need = (eff > last_wait);
            } else if (tid < 72) {
                nx_xm = x_m[(size_t)(b0 + tid - 64) * Ln + tn];
            }
            if (tid < 128) {
                const size_t prow = ((size_t)(b0 + (tid >> 4)) * Ln + tn) * (size_t)PCOLS
                                    + m0 + (tid & 15);
                np0 = P[prow];           np1 = P[prow + Mn];
                np2 = P[prow + 2 * Mn];  np3 = P[prow + 3 * Mn];
            }
        }
        __syncthreads();   // s_io ready for gates

        // ---- gates, c/h, blend vs s_pv, store ----
        if (tid < 128) {
            const int b = tid >> 4, j = tid & 15;
            const float iv = s_io[b * 48 + j]      + p0;
            const float ov = s_io[b * 48 + 16 + j] + p1;
            const float uv = s_io[b * 48 + 32 + j] + p2;
            const float i_ = sigmoidf_(iv);
            const float o_ = sigmoidf_(ov);
            const float u_ = tanhf(uv);
            float facc = 0.f;
            #pragma unroll
            for (int c = 0; c < 8; ++c) {
                const int row = b * 8 + c;
                const float f = sigmoidf_(s_fd[row * 16 + j] + bfh_j + p3);
                facc += f * s_cs[row * 16 + j] * s_xmc[row];
            }
            const float cv = i_ * u_ + facc;
            const float hv = o_ * tanhf(cv);
            const float mv = s_xm[b];
            const float nc = mv * cv + (1.f - mv) * s_pv[b * 32 + j];
            const float nh = mv * hv + (1.f - mv) * s_pv[b * 32 + 16 + j];
            const size_t ob = ((size_t)(b0 + b) * Ln + t) * TWO_M;
            out[ob + m0 + j]      = nc;
            out[ob + Mn + m0 + j] = nh;
            s_pv[b * 32 + j]      = nc;
            s_pv[b * 32 + 16 + j] = nh;
        }

        // ---- conditional group barrier ----
        // All blocks SIGNAL every step (release). Only blocks whose next-step
        // children reach into (last_wait, t] WAIT + ACQUIRE.
        const int anyneed = __syncthreads_or(need);   // also fences gates' stores
        if (t < Ln - 1) {
            if (tid == 0)
                __hip_atomic_fetch_add(myctr, 1u, __ATOMIC_RELEASE, __HIP_MEMORY_SCOPE_AGENT);
            if (anyneed) {
                if (tid == 0) {
                    const unsigned target = 32u * (unsigned)t;
                    while (__hip_atomic_load(myctr, __ATOMIC_RELAXED, __HIP_MEMORY_SCOPE_AGENT) < target)
                        __builtin_amdgcn_s_sleep(2);
                    (void)__hip_atomic_load(myctr, __ATOMIC_ACQUIRE, __HIP_MEMORY_SCOPE_AGENT);
                }
                __syncthreads();
                last_wait = t;
            }
        }
        // rotate prefetched registers
        sc_idx = nx_idx; sc_xmc = nx_xmc; sc_xm = nx_xm;
        p0 = np0; p1 = np1; p2 = np2; p3 = np3;
    }
}

// ============================================================================
// Legacy monolithic step kernel (fallback when ws is too small for P)
// ============================================================================
constexpr int LBT = 4, LMT = 32, LNMT = Mn / LMT, LPAD = 4, LDK = Dn + LPAD;
constexpr int L_U16 = 4096, L_CHS = LBT * LDK, L_CH = LBT * Cn * LDK,
              L_WFH = LMT * LDK, L_CS = LBT * Cn * LMT, L_IOUF = 4 * LBT * LMT;
constexpr int L_FLOATS = L_U16 + L_CHS + L_CH + L_WFH + L_CS + L_IOUF + 32 + 4 + 32;
constexpr size_t L_BYTES = (size_t)L_FLOATS * 4;

__global__ __launch_bounds__(256, 1)
void step_legacy(const float* __restrict__ x, const int* __restrict__ x_c,
                 const float* __restrict__ x_m, const float* __restrict__ x_m_c,
                 const float* __restrict__ W_ioux, const float* __restrict__ b_ioux,
                 const float* __restrict__ W_iouh, const float* __restrict__ b_iouh,
                 const float* __restrict__ W_fx, const float* __restrict__ b_fx,
                 const float* __restrict__ W_fh, const float* __restrict__ b_fh,
                 float* __restrict__ out, int t)
{
    extern __shared__ float lds[];
    float* u16    = lds;
    float* s_chs  = u16 + L_U16;
    float* s_ch   = s_chs + L_CHS;
    float* s_wfh  = s_ch + L_CH;
    float* s_cs   = s_wfh + L_WFH;
    float* s_iouf = s_cs + L_CS;
    float* s_xmc  = s_iouf + L_IOUF;
    float* s_xm   = s_xmc + 32;
    int*   s_xc   = (int*)(s_xm + 4);

    const int tid = threadIdx.x;
    const int mt = blockIdx.x & (LNMT - 1);
    const int bt = blockIdx.x >> 4;
    const int b0 = bt * LBT, m0 = mt * LMT;

    #pragma unroll
    for (int i = 0; i < 8; ++i) {
        int flat = i * 256 + tid, b = flat >> 9, k = flat & 511;
        u16[b * LDK + k] = x[((size_t)(b0 + b) * Ln + t) * Dn + k];
    }
    if (tid < 32) {
        int b = tid >> 3, c = tid & 7;
        s_xc[tid]  = x_c[((size_t)(b0 + b) * Ln + t) * Cn + c];
        s_xmc[tid] = x_m_c[((size_t)(b0 + b) * Ln + t) * Cn + c];
    }
    if (tid < 4) s_xm[tid] = x_m[(size_t)(b0 + tid) * Ln + t];
    for (int i = 0; i < 64; ++i) {
        int flat = i * 256 + tid, j = flat >> 9, k = flat & 511;
        s_wfh[j * LDK + k] = W_fh[(size_t)(m0 + j) * Dn + k];
    }
    __syncthreads();

    #pragma unroll
    for (int i = 0; i < 8; ++i) {
        int flat = i * 256 + tid, b = flat >> 9, k = flat & 511;
        float acc = 0.f;
        #pragma unroll
        for (int c = 0; c < 8; ++c) {
            int idx = s_xc[b * 8 + c];
            float v = 0.f;
            if (idx < t) v = out[((size_t)(b0 + b) * Ln + idx) * TWO_M + Mn + k];
            s_ch[(b * 8 + c) * LDK + k] = v;
            acc += s_xmc[b * 8 + c] * v;
        }
        s_chs[b * LDK + k] = acc;
    }
    #pragma unroll
    for (int i = 0; i < 4; ++i) {
        int flat = i * 256 + tid;
        int b = flat >> 8, rem = flat & 255, c = rem >> 5, j = rem & 31;
        int idx = s_xc[b * 8 + c];
        float v = 0.f;
        if (idx < t) v = out[((size_t)(b0 + b) * Ln + idx) * TWO_M + m0 + j];
        s_cs[flat] = v;
    }
    __syncthreads();

    {
        const int unit = tid >> 3, ksl = tid & 7, s = unit >> 3, jg = unit & 7;
        float acc[4][4];
        #pragma unroll
        for (int b = 0; b < 4; ++b)
            #pragma unroll
            for (int jj = 0; jj < 4; ++jj) acc[b][jj] = 0.f;
        if (s < 3) {
            const int colbase = s * Mn + m0 + jg * 4;
            #pragma unroll 4
            for (int it = 0; it < 16; ++it) {
                const int k = it * 32 + ksl * 4;
                float4 sx[4], sc[4];
                #pragma unroll
                for (int b = 0; b < 4; ++b) {
                    sx[b] = *(const float4*)&u16[b * LDK + k];
                    sc[b] = *(const float4*)&s_chs[b * LDK + k];
                }
                #pragma unroll
                for (int jj = 0; jj < 4; ++jj) {
                    const float4 wx = *(const float4*)&W_ioux[(size_t)(colbase + jj) * Dn + k];
                    const float4 wh = *(const float4*)&W_iouh[(size_t)(colbase + jj) * Dn + k];
                    #pragma unroll
                    for (int b = 0; b < 4; ++b)
                        acc[b][jj] += dot4_(sx[b], wx) + dot4_(sc[b], wh);
                }
            }
        } else {
            const int colbase = m0 + jg * 4;
            #pragma unroll 4
            for (int it = 0; it < 16; ++it) {
                const int k = it * 32 + ksl * 4;
                float4 sx[4];
                #pragma unroll
                for (int b = 0; b < 4; ++b) sx[b] = *(const float4*)&u16[b * LDK + k];
                #pragma unroll
                for (int jj = 0; jj < 4; ++jj) {
                    const float4 wx = *(const float4*)&W_fx[(size_t)(colbase + jj) * Dn + k];
                    #pragma unroll
                    for (int b = 0; b < 4; ++b) acc[b][jj] += dot4_(sx[b], wx);
                }
            }
        }
        __syncthreads();
        #pragma unroll
        for (int b = 0; b < 4; ++b)
            #pragma unroll
            for (int jj = 0; jj < 4; ++jj)
                u16[unit * 128 + ksl * 16 + b * 4 + jj] = acc[b][jj];
        __syncthreads();
        #pragma unroll
        for (int e = 0; e < 2; ++e) {
            const int task = e * 256 + tid;
            const int unit2 = task >> 4, rem = task & 15;
            float v = 0.f;
            #pragma unroll
            for (int k2 = 0; k2 < 8; ++k2) v += u16[unit2 * 128 + k2 * 16 + rem];
            const int s2 = unit2 >> 3, jg2 = unit2 & 7;
            const int bb = rem >> 2, jj = rem & 3, j = jg2 * 4 + jj;
            float bias = (s2 < 3) ? (b_ioux[s2 * Mn + m0 + j] + b_iouh[s2 * Mn + m0 + j])
                                  : b_fx[m0 + j];
            s_iouf[(s2 * 4 + bb) * 32 + j] = v + bias;
        }
    }
    __syncthreads();

    {
        const int pos = tid >> 2, ksc = tid & 3, rg = pos >> 3, jg = pos & 7;
        float acc[4][4];
        #pragma unroll
        for (int r = 0; r < 4; ++r)
            #pragma unroll
            for (int j = 0; j < 4; ++j) acc[r][j] = 0.f;
        #pragma unroll 4
        for (int it = 0; it < 32; ++it) {
            const int k = it * 16 + ksc * 4;
            float4 ch[4], wf[4];
            #pragma unroll
            for (int r = 0; r < 4; ++r) ch[r] = *(const float4*)&s_ch[(rg * 4 + r) * LDK + k];
            #pragma unroll
            for (int j = 0; j < 4; ++j) wf[j] = *(const float4*)&s_wfh[(jg * 4 + j) * LDK + k];
            #pragma unroll
            for (int r = 0; r < 4; ++r)
                #pragma unroll
                for (int j = 0; j < 4; ++j) acc[r][j] += dot4_(ch[r], wf[j]);
        }
        #pragma unroll
        for (int r = 0; r < 4; ++r)
            #pragma unroll
            for (int j = 0; j < 4; ++j)
                u16[((rg * 4 + r) * 32 + (jg * 4 + j)) * 4 + ksc] = acc[r][j];
    }
    __syncthreads();

    if (tid < 128) {
        const int b = tid >> 5, j = tid & 31;
        const float iv  = s_iouf[(0 * 4 + b) * 32 + j];
        const float ov  = s_iouf[(1 * 4 + b) * 32 + j];
        const float uv  = s_iouf[(2 * 4 + b) * 32 + j];
        const float fxv = s_iouf[(3 * 4 + b) * 32 + j];
        const float i_ = sigmoidf_(iv), o_ = sigmoidf_(ov), u_ = tanhf(uv);
        const float bfh = b_fh[m0 + j];
        float facc = 0.f;
        #pragma unroll
        for (int c = 0; c < 8; ++c) {
            const int row = b * 8 + c;
            const float fd = u16[(row * 32 + j) * 4 + 0] + u16[(row * 32 + j) * 4 + 1]
                           + u16[(row * 32 + j) * 4 + 2] + u16[(row * 32 + j) * 4 + 3];
            const float f = sigmoidf_(fd + bfh + fxv);
            facc += f * s_cs[row * 32 + j] * s_xmc[row];
        }
        const float cval = i_ * u_ + facc;
        const float hval = o_ * tanhf(cval);
        const float mval = s_xm[b];
        const size_t base  = ((size_t)(b0 + b) * Ln + t) * TWO_M;
        const size_t pbase = ((size_t)(b0 + b) * Ln + (t - 1)) * TWO_M;
        out[base + m0 + j]      = mval * cval + (1.f - mval) * out[pbase + m0 + j];
        out[base + Mn + m0 + j] = mval * hval + (1.f - mval) * out[pbase + Mn + m0 + j];
    }
}

__global__ void zero_row0(float* __restrict__ out) {
    int i = blockIdx.x * 256 + threadIdx.x;
    int b = i >> 10, j = i & 1023;
    out[(size_t)b * Ln * TWO_M + j] = 0.f;
}

__global__ void zero_ctr(unsigned* __restrict__ c) {
    if (threadIdx.x < 8) c[threadIdx.x * 32] = 0u;
}

__global__ void final_copy(const float* __restrict__ out, float* __restrict__ fin) {
    int i = blockIdx.x * 256 + threadIdx.x;
    int b = i >> 10, j = i & 1023;
    fin[i] = out[((size_t)b * Ln + (Ln - 1)) * TWO_M + j];
}

} // namespace

extern "C" void kernel_launch(void* const* d_in, const int* in_sizes, int n_in,
                              void* d_out, int out_size, void* d_ws, size_t ws_size,
                              hipStream_t stream) {
    (void)in_sizes; (void)n_in; (void)out_size;
    const float* x      = (const float*)d_in[0];
    const int*   x_c    = (const int*)d_in[1];
    const float* x_m    = (const float*)d_in[2];
    const float* x_m_c  = (const float*)d_in[3];
    const float* W_ioux = (const float*)d_in[4];
    const float* b_ioux = (const float*)d_in[5];
    const float* W_iouh = (const float*)d_in[6];
    const float* b_iouh = (const float*)d_in[7];
    const float* W_fx   = (const float*)d_in[8];
    const float* b_fx   = (const float*)d_in[9];
    const float* W_fh   = (const float*)d_in[10];
    const float* b_fh   = (const float*)d_in[11];
    float* out = (float*)d_out;
    float* fin = out + (size_t)Bn * Ln * TWO_M;

    hipFuncSetAttribute((const void*)persist10_kernel,
                        hipFuncAttributeMaxDynamicSharedMemorySize, (int)R_LDS_BYTES);
    hipFuncSetAttribute((const void*)step_legacy,
                        hipFuncAttributeMaxDynamicSharedMemorySize, (int)L_BYTES);

    hipLaunchKernelGGL(zero_row0, dim3(256), dim3(256), 0, stream, out);

    if (ws_size >= P_BYTES) {
        float* Pp = (float*)d_ws;
        // barrier counters overlap P row (b=0,t=0), which no step reads.
        unsigned* ctr = (unsigned*)d_ws;
        hipLaunchKernelGGL(proj2_kernel, dim3(8192), dim3(256), 0, stream,
                           x, W_ioux, b_ioux, b_iouh, W_fx, b_fx, Pp);
        hipLaunchKernelGGL(zero_ctr, dim3(1), dim3(64), 0, stream, ctr);
        void* kargs[] = { (void*)&x_c, (void*)&x_m, (void*)&x_m_c, (void*)&W_iouh,
                          (void*)&W_fh, (void*)&b_fh, (void*)&Pp, (void*)&out,
                          (void*)&ctr };
        hipLaunchCooperativeKernel((const void*)persist10_kernel, dim3(256), dim3(512),
                                   kargs, (unsigned)R_LDS_BYTES, stream);
    } else {
        for (int t = 1; t < Ln; ++t) {
            hipLaunchKernelGGL(step_legacy, dim3(256), dim3(256), L_BYTES, stream,
                               x, x_c, x_m, x_m_c, W_ioux, b_ioux, W_iouh, b_iouh,
                               W_fx, b_fx, W_fh, b_fh, out, t);
        }
    }
    hipLaunchKernelGGL(final_copy, dim3(256), dim3(256), 0, stream, out, fin);
}